// Round 6
// baseline (143.597 us; speedup 1.0000x reference)
//
#include <hip/hip_runtime.h>

#define RES 128
#define NCELLS (RES * RES * RES)        // 2097152
#define CASC 4
#define GRID_TOTAL (CASC * NCELLS)      // 8388608
#define NBYTES (GRID_TOTAL / 8)         // 1048576

// inverse of instant-ngp expand_bits: gather every 3rd bit
__device__ __forceinline__ unsigned compact3(unsigned v) {
    v &= 0x49249249u;
    v = (v | (v >> 2))  & 0xC30C30C3u;
    v = (v | (v >> 4))  & 0x0F00F00Fu;
    v = (v | (v >> 8))  & 0xFF0000FFu;
    v = (v | (v >> 16)) & 0x3FFu;
    return v;
}

// One thread per morton index m; handles all 4 cascades.
// Weights staged in LDS once per block: inner loop = ds_read (imm offset) + fma only.
__global__ __launch_bounds__(256) void dg_main(
    const float* __restrict__ dgrid,   // [CASC, NCELLS]
    const float* __restrict__ jit,     // [CASC, NCELLS, 3]
    const float* __restrict__ W1,      // [3,32]
    const float* __restrict__ b1,      // [32]
    const float* __restrict__ W2,      // [32]
    const float* __restrict__ b2,      // [1]
    float* __restrict__ out,           // [CASC, NCELLS]
    double* __restrict__ sum_ws)
{
    // stage weights: w_lds[j*5+{0,1,2,3,4}] = {W1[j], W1[32+j], W1[64+j], b1[j], W2[j]}
    __shared__ float w_lds[160];
    if (threadIdx.x < 32) {
        const int j = threadIdx.x;
        w_lds[j * 5 + 0] = W1[j];
        w_lds[j * 5 + 1] = W1[32 + j];
        w_lds[j * 5 + 2] = W1[64 + j];
        w_lds[j * 5 + 3] = b1[j];
        w_lds[j * 5 + 4] = W2[j];
    }
    __syncthreads();

    const int m = blockIdx.x * 256 + threadIdx.x;
    const unsigned x = compact3((unsigned)m);
    const unsigned y = compact3((unsigned)m >> 1);
    const unsigned z = compact3((unsigned)m >> 2);
    const int c = (int)((x << 14) | (y << 7) | z);   // linear cell index

    const float cx = (float)x, cy = (float)y, cz = (float)z;
    const float bb2 = b2[0];

    double lsum = 0.0;

    #pragma unroll
    for (int lvl = 0; lvl < CASC; ++lvl) {
        const float scale = (float)(1 << lvl);
        const float* jp = jit + ((size_t)lvl * NCELLS + (size_t)c) * 3;
        const float jx = jp[0], jy = jp[1], jz = jp[2];
        // x = ((cf + jitter)/128 - 0.5) * 2^lvl   (all steps exact or same-rounded as ref)
        const float px = ((cx + jx) * (1.0f / 128.0f) - 0.5f) * scale;
        const float py = ((cy + jy) * (1.0f / 128.0f) - 0.5f) * scale;
        const float pz = ((cz + jz) * (1.0f / 128.0f) - 0.5f) * scale;

        float acc = bb2;
        #pragma unroll
        for (int j = 0; j < 32; ++j) {
            float a = w_lds[j * 5 + 3];                  // b1[j]
            a = fmaf(px, w_lds[j * 5 + 0], a);           // W1[j]
            a = fmaf(py, w_lds[j * 5 + 1], a);           // W1[32+j]
            a = fmaf(pz, w_lds[j * 5 + 2], a);           // W1[64+j]
            a = fmaxf(a, 0.0f);                          // relu
            acc = fmaf(a, w_lds[j * 5 + 4], acc);        // W2[j]
        }
        // softplus(acc) = max(acc,0) + log1p(exp(-|acc|))   (jax.nn.softplus form)
        const float d = fmaxf(acc, 0.0f) + log1pf(expf(-fabsf(acc)));

        const float g = dgrid[(size_t)lvl * NCELLS + m];
        const float nv = (g >= 0.0f && d >= 0.0f) ? fmaxf(g * 0.95f, d) : g;
        out[(size_t)lvl * NCELLS + m] = nv;
        lsum += (double)nv;
    }

    // block reduction (f64) then one atomicAdd per block
    __shared__ double sdata[256];
    sdata[threadIdx.x] = lsum;
    __syncthreads();
    #pragma unroll
    for (int s = 128; s > 0; s >>= 1) {
        if (threadIdx.x < s) sdata[threadIdx.x] += sdata[threadIdx.x + s];
        __syncthreads();
    }
    if (threadIdx.x == 0) atomicAdd(sum_ws, sdata[0]);
}

__global__ void dg_finalize(const double* __restrict__ sum_ws,
                            float* __restrict__ out,
                            float* __restrict__ thr_ws)
{
    const double mean = *sum_ws / (double)GRID_TOTAL;
    const float mf = (float)mean;
    out[GRID_TOTAL] = mf;                 // mean_density output
    *thr_ws = fminf(mf, 2.0f);            // thresh for bitfield pass
}

// One thread per output byte: read 8 consecutive grid floats, pack bits, emit as float.
__global__ __launch_bounds__(256) void dg_bitfield(
    const float* __restrict__ grid,
    const float* __restrict__ thr_ws,
    float* __restrict__ outb)
{
    const int i = blockIdx.x * 256 + threadIdx.x;
    const float t = *thr_ws;
    const float4* p = (const float4*)(grid + (size_t)i * 8);
    const float4 a = p[0];
    const float4 b = p[1];
    int v = 0;
    v |= (a.x > t) ? 1   : 0;
    v |= (a.y > t) ? 2   : 0;
    v |= (a.z > t) ? 4   : 0;
    v |= (a.w > t) ? 8   : 0;
    v |= (b.x > t) ? 16  : 0;
    v |= (b.y > t) ? 32  : 0;
    v |= (b.z > t) ? 64  : 0;
    v |= (b.w > t) ? 128 : 0;
    outb[i] = (float)v;
}

extern "C" void kernel_launch(void* const* d_in, const int* in_sizes, int n_in,
                              void* d_out, int out_size, void* d_ws, size_t ws_size,
                              hipStream_t stream) {
    const float* dgrid = (const float*)d_in[0];
    const float* jit   = (const float*)d_in[1];
    const float* W1    = (const float*)d_in[2];
    const float* b1    = (const float*)d_in[3];
    const float* W2    = (const float*)d_in[4];
    const float* b2    = (const float*)d_in[5];

    float* out = (float*)d_out;
    double* sum_ws = (double*)d_ws;
    float* thr_ws = (float*)((char*)d_ws + 8);

    hipMemsetAsync(d_ws, 0, 8, stream);   // zero the f64 accumulator (capture-safe)

    dg_main<<<NCELLS / 256, 256, 0, stream>>>(dgrid, jit, W1, b1, W2, b2, out, sum_ws);
    dg_finalize<<<1, 1, 0, stream>>>(sum_ws, out, thr_ws);
    dg_bitfield<<<NBYTES / 256, 256, 0, stream>>>(out, thr_ws, out + GRID_TOTAL + 1);
}

// Round 7
// 143.013 us; speedup vs baseline: 1.0041x; 1.0041x over previous
//
#include <hip/hip_runtime.h>

#define RES 128
#define NCELLS (RES * RES * RES)        // 2097152
#define CASC 4
#define GRID_TOTAL (CASC * NCELLS)      // 8388608
#define NBYTES (GRID_TOTAL / 8)         // 1048576

// inverse of instant-ngp expand_bits: gather every 3rd bit
__device__ __forceinline__ unsigned compact3(unsigned v) {
    v &= 0x49249249u;
    v = (v | (v >> 2))  & 0xC30C30C3u;
    v = (v | (v >> 4))  & 0x0F00F00Fu;
    v = (v | (v >> 8))  & 0xFF0000FFu;
    v = (v | (v >> 16)) & 0x3FFu;
    return v;
}

// One thread per morton index m; handles all 4 cascades.
// Weights in LDS as float4 (one ds_read_b128 + one ds_read_b32 per j).
__global__ __launch_bounds__(256) void dg_main(
    const float* __restrict__ dgrid,   // [CASC, NCELLS]
    const float* __restrict__ jit,     // [CASC, NCELLS, 3]
    const float* __restrict__ W1,      // [3,32]
    const float* __restrict__ b1,      // [32]
    const float* __restrict__ W2,      // [32]
    const float* __restrict__ b2,      // [1]
    float* __restrict__ out,           // [CASC, NCELLS]
    double* __restrict__ sum_ws)
{
    // wq[j] = {W1[j], W1[32+j], W1[64+j], b1[j]};  w2s[j] = W2[j]
    __shared__ float4 wq[32];
    __shared__ float w2s[32];
    if (threadIdx.x < 32) {
        const int j = threadIdx.x;
        wq[j] = make_float4(W1[j], W1[32 + j], W1[64 + j], b1[j]);
        w2s[j] = W2[j];
    }
    __syncthreads();

    const int m = blockIdx.x * 256 + threadIdx.x;
    const unsigned x = compact3((unsigned)m);
    const unsigned y = compact3((unsigned)m >> 1);
    const unsigned z = compact3((unsigned)m >> 2);
    const int c = (int)((x << 14) | (y << 7) | z);   // linear cell index

    const float cx = (float)x, cy = (float)y, cz = (float)z;
    const float bb2 = b2[0];

    double lsum = 0.0;

    #pragma unroll
    for (int lvl = 0; lvl < CASC; ++lvl) {
        const float scale = (float)(1 << lvl);
        const float* jp = jit + ((size_t)lvl * NCELLS + (size_t)c) * 3;
        const float jx = jp[0], jy = jp[1], jz = jp[2];
        // x = ((cf + jitter)/128 - 0.5) * 2^lvl   (all steps exact or same-rounded as ref)
        const float px = ((cx + jx) * (1.0f / 128.0f) - 0.5f) * scale;
        const float py = ((cy + jy) * (1.0f / 128.0f) - 0.5f) * scale;
        const float pz = ((cz + jz) * (1.0f / 128.0f) - 0.5f) * scale;

        float acc = bb2;
        #pragma unroll
        for (int j = 0; j < 32; ++j) {
            const float4 w = wq[j];
            float a = w.w;                    // b1[j]
            a = fmaf(px, w.x, a);             // W1[j]
            a = fmaf(py, w.y, a);             // W1[32+j]
            a = fmaf(pz, w.z, a);             // W1[64+j]
            a = fmaxf(a, 0.0f);               // relu
            acc = fmaf(a, w2s[j], acc);       // W2[j]
        }
        // softplus(acc) = max(acc,0) + log1p(exp(-|acc|))   (jax.nn.softplus form)
        const float d = fmaxf(acc, 0.0f) + log1pf(expf(-fabsf(acc)));

        const float g = dgrid[(size_t)lvl * NCELLS + m];
        const float nv = (g >= 0.0f && d >= 0.0f) ? fmaxf(g * 0.95f, d) : g;
        out[(size_t)lvl * NCELLS + m] = nv;
        lsum += (double)nv;
    }

    // block reduction (f64) then one atomicAdd per block
    __shared__ double sdata[256];
    sdata[threadIdx.x] = lsum;
    __syncthreads();
    #pragma unroll
    for (int s = 128; s > 0; s >>= 1) {
        if (threadIdx.x < s) sdata[threadIdx.x] += sdata[threadIdx.x + s];
        __syncthreads();
    }
    if (threadIdx.x == 0) atomicAdd(sum_ws, sdata[0]);
}

__global__ void dg_finalize(const double* __restrict__ sum_ws,
                            float* __restrict__ out,
                            float* __restrict__ thr_ws)
{
    const double mean = *sum_ws / (double)GRID_TOTAL;
    const float mf = (float)mean;
    out[GRID_TOTAL] = mf;                 // mean_density output
    *thr_ws = fminf(mf, 2.0f);            // thresh for bitfield pass
}

// One thread per output byte: read 8 consecutive grid floats, pack bits, emit as float.
__global__ __launch_bounds__(256) void dg_bitfield(
    const float* __restrict__ grid,
    const float* __restrict__ thr_ws,
    float* __restrict__ outb)
{
    const int i = blockIdx.x * 256 + threadIdx.x;
    const float t = *thr_ws;
    const float4* p = (const float4*)(grid + (size_t)i * 8);
    const float4 a = p[0];
    const float4 b = p[1];
    int v = 0;
    v |= (a.x > t) ? 1   : 0;
    v |= (a.y > t) ? 2   : 0;
    v |= (a.z > t) ? 4   : 0;
    v |= (a.w > t) ? 8   : 0;
    v |= (b.x > t) ? 16  : 0;
    v |= (b.y > t) ? 32  : 0;
    v |= (b.z > t) ? 64  : 0;
    v |= (b.w > t) ? 128 : 0;
    outb[i] = (float)v;
}

extern "C" void kernel_launch(void* const* d_in, const int* in_sizes, int n_in,
                              void* d_out, int out_size, void* d_ws, size_t ws_size,
                              hipStream_t stream) {
    const float* dgrid = (const float*)d_in[0];
    const float* jit   = (const float*)d_in[1];
    const float* W1    = (const float*)d_in[2];
    const float* b1    = (const float*)d_in[3];
    const float* W2    = (const float*)d_in[4];
    const float* b2    = (const float*)d_in[5];

    float* out = (float*)d_out;
    double* sum_ws = (double*)d_ws;
    float* thr_ws = (float*)((char*)d_ws + 8);

    hipMemsetAsync(d_ws, 0, 8, stream);   // zero the f64 accumulator (capture-safe)

    dg_main<<<NCELLS / 256, 256, 0, stream>>>(dgrid, jit, W1, b1, W2, b2, out, sum_ws);
    dg_finalize<<<1, 1, 0, stream>>>(sum_ws, out, thr_ws);
    dg_bitfield<<<NBYTES / 256, 256, 0, stream>>>(out, thr_ws, out + GRID_TOTAL + 1);
}

// Round 9
// 128.924 us; speedup vs baseline: 1.1138x; 1.1093x over previous
//
#include <hip/hip_runtime.h>

#define RES 128
#define NCELLS (RES * RES * RES)        // 2097152
#define CASC 4
#define GRID_TOTAL (CASC * NCELLS)      // 8388608
#define NBYTES (GRID_TOTAL / 8)         // 1048576

// inverse of instant-ngp expand_bits: gather every 3rd bit
__device__ __forceinline__ unsigned compact3(unsigned v) {
    v &= 0x49249249u;
    v = (v | (v >> 2))  & 0xC30C30C3u;
    v = (v | (v >> 4))  & 0x0F00F00Fu;
    v = (v | (v >> 8))  & 0xFF0000FFu;
    v = (v | (v >> 16)) & 0x3FFu;
    return v;
}

// One thread per morton index m; handles all 4 cascades.
// All 160 weight floats hoisted from LDS into named registers once; the MLP
// inner loops are then pure VALU (no per-iteration memory stalls).
__global__ __launch_bounds__(256, 2) void dg_main(
    const float* __restrict__ dgrid,   // [CASC, NCELLS]
    const float* __restrict__ jit,     // [CASC, NCELLS, 3]
    const float* __restrict__ W1,      // [3,32]
    const float* __restrict__ b1,      // [32]
    const float* __restrict__ W2,      // [32]
    const float* __restrict__ b2,      // [1]
    float* __restrict__ out,           // [CASC, NCELLS]
    double* __restrict__ sum_ws)
{
    // wq[j] = {W1[j], W1[32+j], W1[64+j], b1[j]};  w2s[j] = W2[j]
    __shared__ float4 wq[32];
    __shared__ float w2s[32];
    if (threadIdx.x < 32) {
        const int j = threadIdx.x;
        wq[j] = make_float4(W1[j], W1[32 + j], W1[64 + j], b1[j]);
        w2s[j] = W2[j];
    }
    __syncthreads();

    const int m = blockIdx.x * 256 + threadIdx.x;
    const unsigned x = compact3((unsigned)m);
    const unsigned y = compact3((unsigned)m >> 1);
    const unsigned z = compact3((unsigned)m >> 2);
    const int c = (int)((x << 14) | (y << 7) | z);   // linear cell index

    const float cx = (float)x, cy = (float)y, cz = (float)z;
    const float bb2 = b2[0];

    // ---- hoisted global loads (issued together; latency exposed once) ----
    const float* jp0 = jit + ((size_t)0 * NCELLS + (size_t)c) * 3;
    const float* jp1 = jit + ((size_t)1 * NCELLS + (size_t)c) * 3;
    const float* jp2 = jit + ((size_t)2 * NCELLS + (size_t)c) * 3;
    const float* jp3 = jit + ((size_t)3 * NCELLS + (size_t)c) * 3;
    const float jx0 = jp0[0], jy0 = jp0[1], jz0 = jp0[2];
    const float jx1 = jp1[0], jy1 = jp1[1], jz1 = jp1[2];
    const float jx2 = jp2[0], jy2 = jp2[1], jz2 = jp2[2];
    const float jx3 = jp3[0], jy3 = jp3[1], jz3 = jp3[2];
    const float g0 = dgrid[(size_t)0 * NCELLS + m];
    const float g1 = dgrid[(size_t)1 * NCELLS + m];
    const float g2 = dgrid[(size_t)2 * NCELLS + m];
    const float g3 = dgrid[(size_t)3 * NCELLS + m];

    // ---- hoist all weights into named registers (names avoid W1/W2 params) ----
#define WLOAD(J) const float4 RW##J = wq[J]; const float RU##J = w2s[J];
    WLOAD(0)  WLOAD(1)  WLOAD(2)  WLOAD(3)  WLOAD(4)  WLOAD(5)  WLOAD(6)  WLOAD(7)
    WLOAD(8)  WLOAD(9)  WLOAD(10) WLOAD(11) WLOAD(12) WLOAD(13) WLOAD(14) WLOAD(15)
    WLOAD(16) WLOAD(17) WLOAD(18) WLOAD(19) WLOAD(20) WLOAD(21) WLOAD(22) WLOAD(23)
    WLOAD(24) WLOAD(25) WLOAD(26) WLOAD(27) WLOAD(28) WLOAD(29) WLOAD(30) WLOAD(31)
#undef WLOAD

    // same fma order as reference: a = b1; a=fma(px,W1r0,a); py; pz; relu; acc=fma(a,W2,acc)
#define MSTEP(J) { float a_ = fmaf(px, RW##J.x, RW##J.w); \
                   a_ = fmaf(py, RW##J.y, a_); \
                   a_ = fmaf(pz, RW##J.z, a_); \
                   a_ = fmaxf(a_, 0.0f); \
                   acc = fmaf(a_, RU##J, acc); }
#define MLP_ALL \
    MSTEP(0)  MSTEP(1)  MSTEP(2)  MSTEP(3)  MSTEP(4)  MSTEP(5)  MSTEP(6)  MSTEP(7) \
    MSTEP(8)  MSTEP(9)  MSTEP(10) MSTEP(11) MSTEP(12) MSTEP(13) MSTEP(14) MSTEP(15) \
    MSTEP(16) MSTEP(17) MSTEP(18) MSTEP(19) MSTEP(20) MSTEP(21) MSTEP(22) MSTEP(23) \
    MSTEP(24) MSTEP(25) MSTEP(26) MSTEP(27) MSTEP(28) MSTEP(29) MSTEP(30) MSTEP(31)

    double lsum = 0.0;

#define LEVEL(L, SCALE, JX, JY, JZ, G) { \
        const float px = ((cx + JX) * (1.0f / 128.0f) - 0.5f) * SCALE; \
        const float py = ((cy + JY) * (1.0f / 128.0f) - 0.5f) * SCALE; \
        const float pz = ((cz + JZ) * (1.0f / 128.0f) - 0.5f) * SCALE; \
        float acc = bb2; \
        MLP_ALL \
        const float d = fmaxf(acc, 0.0f) + log1pf(expf(-fabsf(acc))); \
        const float nv = (G >= 0.0f && d >= 0.0f) ? fmaxf(G * 0.95f, d) : G; \
        out[(size_t)L * NCELLS + m] = nv; \
        lsum += (double)nv; }

    LEVEL(0, 1.0f, jx0, jy0, jz0, g0)
    LEVEL(1, 2.0f, jx1, jy1, jz1, g1)
    LEVEL(2, 4.0f, jx2, jy2, jz2, g2)
    LEVEL(3, 8.0f, jx3, jy3, jz3, g3)
#undef LEVEL
#undef MLP_ALL
#undef MSTEP

    // block reduction (f64) then one atomicAdd per block
    __shared__ double sdata[256];
    sdata[threadIdx.x] = lsum;
    __syncthreads();
    #pragma unroll
    for (int s = 128; s > 0; s >>= 1) {
        if (threadIdx.x < s) sdata[threadIdx.x] += sdata[threadIdx.x + s];
        __syncthreads();
    }
    if (threadIdx.x == 0) atomicAdd(sum_ws, sdata[0]);
}

__global__ void dg_finalize(const double* __restrict__ sum_ws,
                            float* __restrict__ out,
                            float* __restrict__ thr_ws)
{
    const double mean = *sum_ws / (double)GRID_TOTAL;
    const float mf = (float)mean;
    out[GRID_TOTAL] = mf;                 // mean_density output
    *thr_ws = fminf(mf, 2.0f);            // thresh for bitfield pass
}

// One thread per output byte: read 8 consecutive grid floats, pack bits, emit as float.
__global__ __launch_bounds__(256) void dg_bitfield(
    const float* __restrict__ grid,
    const float* __restrict__ thr_ws,
    float* __restrict__ outb)
{
    const int i = blockIdx.x * 256 + threadIdx.x;
    const float t = *thr_ws;
    const float4* p = (const float4*)(grid + (size_t)i * 8);
    const float4 a = p[0];
    const float4 b = p[1];
    int v = 0;
    v |= (a.x > t) ? 1   : 0;
    v |= (a.y > t) ? 2   : 0;
    v |= (a.z > t) ? 4   : 0;
    v |= (a.w > t) ? 8   : 0;
    v |= (b.x > t) ? 16  : 0;
    v |= (b.y > t) ? 32  : 0;
    v |= (b.z > t) ? 64  : 0;
    v |= (b.w > t) ? 128 : 0;
    outb[i] = (float)v;
}

extern "C" void kernel_launch(void* const* d_in, const int* in_sizes, int n_in,
                              void* d_out, int out_size, void* d_ws, size_t ws_size,
                              hipStream_t stream) {
    const float* dgrid = (const float*)d_in[0];
    const float* jit   = (const float*)d_in[1];
    const float* W1    = (const float*)d_in[2];
    const float* b1    = (const float*)d_in[3];
    const float* W2    = (const float*)d_in[4];
    const float* b2    = (const float*)d_in[5];

    float* out = (float*)d_out;
    double* sum_ws = (double*)d_ws;
    float* thr_ws = (float*)((char*)d_ws + 8);

    hipMemsetAsync(d_ws, 0, 8, stream);   // zero the f64 accumulator (capture-safe)

    dg_main<<<NCELLS / 256, 256, 0, stream>>>(dgrid, jit, W1, b1, W2, b2, out, sum_ws);
    dg_finalize<<<1, 1, 0, stream>>>(sum_ws, out, thr_ws);
    dg_bitfield<<<NBYTES / 256, 256, 0, stream>>>(out, thr_ws, out + GRID_TOTAL + 1);
}